// Round 1
// baseline (125.672 us; speedup 1.0000x reference)
//
#include <hip/hip_runtime.h>

// KnnExpansion: out[f, n] = sum_k alpha[i[n,k], f] * exp(-0.5 * d[n,k] / sigma^2)
// N=131072 queries, K=32 neighbors, M=65536 alpha rows, F=64 channels.
//
// Mapping: one wave (64 lanes) per query; lane = channel f.
//  - gather of alpha row is a coalesced 256B load (64 lanes x 4B)
//  - w[k] and idx[k] broadcast via readlane -> SGPR (uniform gather base,
//    SGPR multiplier in the fmac)
//  - 64-query x 64-channel output tile transposed through LDS so the
//    [F, N] store is coalesced (row f: 64 contiguous floats).

#define N_Q 131072
#define K_NB 32
#define F_CH 64

__global__ __launch_bounds__(256) void knn_exp_kernel(
    const float* __restrict__ dmat,   // [N, 32] squared distances
    const int*   __restrict__ imat,   // [N, 32] indices into alpha
    const float* __restrict__ alpha,  // [65536, 64]
    const float* __restrict__ sigma,  // [1]
    float*       __restrict__ out)    // [64, N]
{
    __shared__ float tile[64][65];    // +1 pad: conflict-free column reads

    const int lane = threadIdx.x & 63;
    const int wave = threadIdx.x >> 6;
    const int n0   = blockIdx.x * 64;   // 64 queries per block

    const float s = sigma[0];
    const float c = -0.5f / (s * s);

    // 4 waves x 16 sequential queries = 64 queries per block
    for (int qi = 0; qi < 16; ++qi) {
        const int q = wave * 16 + qi;
        const int n = n0 + q;

        // lanes 0..31 load d (and compute the Gaussian weight),
        // lanes 32..63 load the neighbor index. Two coalesced 128B segments.
        float wv = 0.0f;
        int   iv = 0;
        if (lane < 32) {
            wv = __expf(c * dmat[n * K_NB + lane]);
        } else {
            iv = imat[n * K_NB + (lane - 32)];
        }

        float acc = 0.0f;
        #pragma unroll
        for (int k = 0; k < K_NB; ++k) {
            // compile-time lane -> v_readlane -> SGPR broadcast
            const float wk = __int_as_float(
                __builtin_amdgcn_readlane(__float_as_int(wv), k));
            const int   ik = __builtin_amdgcn_readlane(iv, 32 + k);
            // coalesced 256B row gather: uniform base + lane*4
            acc = fmaf(wk, alpha[(size_t)ik * F_CH + lane], acc);
        }
        tile[q][lane] = acc;
    }

    __syncthreads();

    // Transposed, coalesced store: wave handles 16 channel-rows,
    // each row = 64 contiguous floats of out[f, n0..n0+63].
    // LDS column read tile[lane][f]: addr = lane*65 + f -> bank (lane+f)&31,
    // distinct within each 32-lane half (2-way aliasing across halves = free).
    #pragma unroll
    for (int fi = 0; fi < 16; ++fi) {
        const int f = wave * 16 + fi;
        out[(size_t)f * N_Q + n0 + lane] = tile[lane][f];
    }
}

extern "C" void kernel_launch(void* const* d_in, const int* in_sizes, int n_in,
                              void* d_out, int out_size, void* d_ws, size_t ws_size,
                              hipStream_t stream) {
    const float* dmat  = (const float*)d_in[0];
    const int*   imat  = (const int*)d_in[1];
    const float* alpha = (const float*)d_in[2];
    const float* sigma = (const float*)d_in[3];
    float* out = (float*)d_out;

    dim3 grid(N_Q / 64);   // 2048 blocks
    dim3 block(256);       // 4 waves
    hipLaunchKernelGGL(knn_exp_kernel, grid, block, 0, stream,
                       dmat, imat, alpha, sigma, out);
}